// Round 13
// baseline (380.491 us; speedup 1.0000x reference)
//
#include <hip/hip_runtime.h>
#include <hip/hip_bf16.h>
#include <cstdint>
#include <cstddef>

#define NN 512      // nodes
#define NE 2048     // edges (directed input), symmetrized -> 4096
#define NDIR 4096
#define LL 16       // labels
#define FF 16       // filters
#define MM 8        // filter graph nodes
#define HH 128      // WL hash buckets
#define NIT 3       // WL iterations
#define NFEAT 512   // (NIT+1)*HH
#define TCAP 40960  // max total (root,node) pairs (measured T ~= 35050)
#define ECAP 4096   // per-root internal-edge capacity (hard bound)
#define ROSTRIDE 513
#define PTILE 32    // projsm M-tile
#define BK 16       // projsm K-tile
#define ASTRIDE 40  // 16B-aligned rows -> A-read stays ds_read_b128 (broadcast)
#define NTSTRIDE 40 // nbrT row stride, 16B-aligned
#define EXSTRIDE 132

// ---------------- reach (2-hop egonet masks) as bitmasks ----------------
__global__ void k_reach_init(unsigned* __restrict__ B) {
    int idx = blockIdx.x * blockDim.x + threadIdx.x;
    if (idx >= NN * 16) return;
    int j = idx >> 4, w = idx & 15;
    B[idx] = (w == (j >> 5)) ? (1u << (j & 31)) : 0u;
}

__global__ void k_copy_u32(const unsigned* __restrict__ s, unsigned* __restrict__ d, int n) {
    int i = blockIdx.x * blockDim.x + threadIdx.x;
    if (i < n) d[i] = s[i];
}

__global__ void k_hop_or(const int* __restrict__ ei, const unsigned* __restrict__ Bold,
                         unsigned* __restrict__ Bnew) {
    int idx = blockIdx.x * blockDim.x + threadIdx.x;
    if (idx >= NDIR * 16) return;
    int e = idx >> 4, w = idx & 15;
    int s = ei[e];
    int d = (e < NE) ? ei[e + NE] : ei[e - NE];
    unsigned v = Bold[s * 16 + w];
    if (v) atomicOr(&Bnew[d * 16 + w], v);
}

// ---------------- per-root compaction (one wave per root, ballot prefix) ----------------
__global__ void k_compact(const unsigned* __restrict__ B, int* __restrict__ cnt,
                          short* __restrict__ list16, short* __restrict__ pos16) {
    int i = blockIdx.x;          // 512 blocks
    int lane = threadIdx.x;      // 64 threads
    int wi = i >> 5;
    unsigned bi = 1u << (i & 31);
    int base = 0;
    for (int j0 = 0; j0 < NN; j0 += 64) {
        int j = j0 + lane;
        bool has = (B[j * 16 + wi] & bi) != 0u;
        unsigned long long mask = __ballot(has);
        int pre = __popcll(mask & ((1ull << lane) - 1ull));
        short pos = -1;
        if (has) {
            pos = (short)(base + pre);
            list16[i * NN + pos] = (short)j;
        }
        pos16[i * NN + j] = pos;
        base += __popcll(mask);
    }
    if (lane == 0) cnt[i] = base;
}

__global__ void k_scan(const int* __restrict__ cnt, int* __restrict__ nodeOff) {
    __shared__ int s[NN];
    int t = threadIdx.x;
    s[t] = cnt[t];
    __syncthreads();
    for (int off = 1; off < NN; off <<= 1) {
        int v = (t >= off) ? s[t - off] : 0;
        __syncthreads();
        s[t] += v;
        __syncthreads();
    }
    nodeOff[t + 1] = s[t];
    if (t == 0) nodeOff[0] = 0;
}

// per-root dst-CSR of internal edges + rootOf/nodeIdx tables
__global__ void k_build_csr(const int* __restrict__ ei, const int* __restrict__ cnt,
                            const short* __restrict__ pos16, const short* __restrict__ list16,
                            const int* __restrict__ nodeOff, int* __restrict__ rowOff,
                            short* __restrict__ colIdx, int* __restrict__ rootOf,
                            short* __restrict__ nodeIdx) {
    __shared__ short pos_s[NN];
    __shared__ int indeg[NN + 1];
    int i = blockIdx.x;
    int t = threadIdx.x;  // 128 threads
    int c = cnt[i];
    int pb = nodeOff[i];
    for (int j = t; j < NN; j += 128) pos_s[j] = pos16[i * NN + j];
    for (int u = t; u <= c; u += 128) indeg[u] = 0;
    for (int u = t; u < c; u += 128) {
        int p = pb + u;
        if (p < TCAP) {
            rootOf[p] = i;
            nodeIdx[p] = list16[i * NN + u];
        }
    }
    __syncthreads();
    for (int e = t; e < NDIR; e += 128) {
        int s = ei[e];
        int d = (e < NE) ? ei[e + NE] : ei[e - NE];
        int sc = pos_s[s], dc = pos_s[d];
        if (sc >= 0 && dc >= 0) atomicAdd(&indeg[dc], 1);
    }
    __syncthreads();
    if (t == 0) {
        int run = 0;
        int* ro = rowOff + i * ROSTRIDE;
        for (int u = 0; u < c; ++u) {
            int v = indeg[u];
            ro[u] = run;
            indeg[u] = run;  // becomes cursor
            run += v;
        }
        ro[c] = run;
    }
    __syncthreads();
    short* col = colIdx + (size_t)i * ECAP;
    for (int e = t; e < NDIR; e += 128) {
        int s = ei[e];
        int d = (e < NE) ? ei[e + NE] : ei[e - NE];
        int sc = pos_s[s], dc = pos_s[d];
        if (sc >= 0 && dc >= 0) {
            int slot = atomicAdd(&indeg[dc], 1);
            col[slot] = (short)sc;
        }
    }
}

// ---------------- initial bucket labels ----------------
__global__ void k_c0(const float* __restrict__ x, const float* __restrict__ E0,
                     float* __restrict__ c0_all) {
    int n = blockIdx.x, h = threadIdx.x;
    float s = 0.f;
    for (int l = 0; l < LL; ++l) s += x[n * LL + l] * E0[l * HH + h];
    c0_all[n * HH + h] = s;
}

// feats slot 0: per-root sum of c0 over egonet (exact: 0/1 values), no atomics
__global__ void k_feats0(const int* __restrict__ cnt, const short* __restrict__ list16,
                         const float* __restrict__ c0_all, float* __restrict__ feats) {
    int i = blockIdx.x, h = threadIdx.x;  // 512 x 128
    int c = cnt[i];
    float s = 0.f;
    for (int u = 0; u < c; ++u) s += c0_all[(size_t)list16[i * NN + u] * HH + h];
    feats[i * NFEAT + h] = s;
}

// ---------------- fused WL step: prologue gather + GEMM + softmax + LDS hist ----------------
// Prologue (conflict-free mapping): thread = (pair-row t&31, col-slice (t>>5)*16); walks
// its pair's CSR once, accumulates 16-col slice in registers, writes nbrT[col][row]
// (addr = row40*col + lane&31 -> 32 distinct banks).
// k-loop: 16 K-tiles of BK=16; low-K A staged from srcC into As (b128 broadcast reads);
// high-K A read directly from nbrT. B staged per tile into Bs.
// Histogram: softmax outputs -> exS (union over As/Bs), 128 column-threads merge
// root-runs -> ~256 atomics/block (8x fewer memory-side atomics).
__global__ __launch_bounds__(256) void k_projsm(
    const int* __restrict__ nodeOff, const int* __restrict__ rootOf,
    const int* __restrict__ rowOff, const short* __restrict__ colIdx,
    const short* __restrict__ nidx, const float* __restrict__ srcC,
    const float* __restrict__ R, float* __restrict__ cNext,
    float* __restrict__ feats, int it) {
    __shared__ float nbrT[HH][NTSTRIDE];  // [col][pair-row]
    __shared__ int groots[PTILE];
    // union: GEMM staging (As+Bs) vs post-GEMM histogram buffer exS[32][132]
    __shared__ __align__(16) char usmem[PTILE * EXSTRIDE * 4];  // 16896 B >= As+Bs (11008)
    float (*As)[ASTRIDE] = (float(*)[ASTRIDE])usmem;                       // [BK][40]
    float (*Bs)[EXSTRIDE] = (float(*)[EXSTRIDE])(usmem + BK * ASTRIDE * 4);  // [BK][132]
    float (*exS)[EXSTRIDE] = (float(*)[EXSTRIDE])usmem;                    // [32][132]
    int T = nodeOff[NN];
    if (T > TCAP) T = TCAP;
    int p0 = blockIdx.x * PTILE;
    if (p0 >= T) return;
    int t = threadIdx.x;
    if (t < PTILE) groots[t] = (p0 + t < T) ? rootOf[p0 + t] : -1;
    // ---- prologue: one CSR walk per pair-row, 16-col slice per thread ----
    {
        int gr = t & 31;           // pair row
        int gc0 = (t >> 5) * 16;   // col slice
        float ga[16];
#pragma unroll
        for (int j = 0; j < 16; ++j) ga[j] = 0.f;
        int p = p0 + gr;
        if (p < T) {
            int i = rootOf[p];
            int pb = nodeOff[i];
            int u = p - pb;
            const int* ro = rowOff + i * ROSTRIDE;
            int r0 = ro[u], r1 = ro[u + 1];
            const short* col = colIdx + (size_t)i * ECAP;
            for (int e = r0; e < r1; ++e) {
                int q = pb + col[e];
                int srow = nidx ? (int)nidx[q] : q;
                const float* src = &srcC[(size_t)srow * HH + gc0];
                float4 v0 = *(const float4*)&src[0];
                float4 v1 = *(const float4*)&src[4];
                float4 v2 = *(const float4*)&src[8];
                float4 v3 = *(const float4*)&src[12];
                ga[0] += v0.x;  ga[1] += v0.y;  ga[2] += v0.z;  ga[3] += v0.w;
                ga[4] += v1.x;  ga[5] += v1.y;  ga[6] += v1.z;  ga[7] += v1.w;
                ga[8] += v2.x;  ga[9] += v2.y;  ga[10] += v2.z; ga[11] += v2.w;
                ga[12] += v3.x; ga[13] += v3.y; ga[14] += v3.z; ga[15] += v3.w;
            }
        }
#pragma unroll
        for (int j = 0; j < 16; ++j) nbrT[gc0 + j][t & 31] = ga[j];
    }
    // ---- GEMM: 16 K-tiles ----
    int nt = t & 31;        // cols nt*4..+3
    int mt = t >> 5;        // rows mt*4..+3
    float acc[4][4];
#pragma unroll
    for (int i = 0; i < 4; ++i)
#pragma unroll
        for (int c = 0; c < 4; ++c) acc[i][c] = 0.f;
    for (int kt16 = 0; kt16 < 16; ++kt16) {
        int kt = kt16 * BK;
        __syncthreads();  // protect prev tile reads (and nbrT/groots on first pass)
        if (kt16 < 8 && t < 128) {
            // stage A from srcC (own labels), transposed: 32 rows x 16 k
            int sr = t >> 2;
            int skq = (t & 3) * 4;
            float4 v = make_float4(0.f, 0.f, 0.f, 0.f);
            int p = p0 + sr;
            if (p < T) {
                int srow = nidx ? (int)nidx[p] : p;
                v = *(const float4*)&srcC[(size_t)srow * HH + kt + skq];
            }
            As[skq + 0][sr] = v.x;
            As[skq + 1][sr] = v.y;
            As[skq + 2][sr] = v.z;
            As[skq + 3][sr] = v.w;
        }
        // stage B: 16 k x 128 cols = 512 float4, 2 per thread
#pragma unroll
        for (int j = 0; j < 2; ++j) {
            int f = j * 256 + t;
            int k = f >> 5, c4 = (f & 31) * 4;
            *(float4*)&Bs[k][c4] = *(const float4*)&R[(kt + k) * HH + c4];
        }
        __syncthreads();
        if (kt16 < 8) {
#pragma unroll 4
            for (int k = 0; k < BK; ++k) {
                float4 a = *(const float4*)&As[k][mt * 4];
                float4 b = *(const float4*)&Bs[k][nt * 4];
                acc[0][0] = fmaf(a.x, b.x, acc[0][0]);
                acc[0][1] = fmaf(a.x, b.y, acc[0][1]);
                acc[0][2] = fmaf(a.x, b.z, acc[0][2]);
                acc[0][3] = fmaf(a.x, b.w, acc[0][3]);
                acc[1][0] = fmaf(a.y, b.x, acc[1][0]);
                acc[1][1] = fmaf(a.y, b.y, acc[1][1]);
                acc[1][2] = fmaf(a.y, b.z, acc[1][2]);
                acc[1][3] = fmaf(a.y, b.w, acc[1][3]);
                acc[2][0] = fmaf(a.z, b.x, acc[2][0]);
                acc[2][1] = fmaf(a.z, b.y, acc[2][1]);
                acc[2][2] = fmaf(a.z, b.z, acc[2][2]);
                acc[2][3] = fmaf(a.z, b.w, acc[2][3]);
                acc[3][0] = fmaf(a.w, b.x, acc[3][0]);
                acc[3][1] = fmaf(a.w, b.y, acc[3][1]);
                acc[3][2] = fmaf(a.w, b.z, acc[3][2]);
                acc[3][3] = fmaf(a.w, b.w, acc[3][3]);
            }
        } else {
            const int kb = kt - 128;
#pragma unroll 4
            for (int k = 0; k < BK; ++k) {
                float4 a = *(const float4*)&nbrT[kb + k][mt * 4];
                float4 b = *(const float4*)&Bs[k][nt * 4];
                acc[0][0] = fmaf(a.x, b.x, acc[0][0]);
                acc[0][1] = fmaf(a.x, b.y, acc[0][1]);
                acc[0][2] = fmaf(a.x, b.z, acc[0][2]);
                acc[0][3] = fmaf(a.x, b.w, acc[0][3]);
                acc[1][0] = fmaf(a.y, b.x, acc[1][0]);
                acc[1][1] = fmaf(a.y, b.y, acc[1][1]);
                acc[1][2] = fmaf(a.y, b.z, acc[1][2]);
                acc[1][3] = fmaf(a.y, b.w, acc[1][3]);
                acc[2][0] = fmaf(a.z, b.x, acc[2][0]);
                acc[2][1] = fmaf(a.z, b.y, acc[2][1]);
                acc[2][2] = fmaf(a.z, b.z, acc[2][2]);
                acc[2][3] = fmaf(a.z, b.w, acc[2][3]);
                acc[3][0] = fmaf(a.w, b.x, acc[3][0]);
                acc[3][1] = fmaf(a.w, b.y, acc[3][1]);
                acc[3][2] = fmaf(a.w, b.z, acc[3][2]);
                acc[3][3] = fmaf(a.w, b.w, acc[3][3]);
            }
        }
    }
    // ---- row softmax (32-lane groups share row mt*4+i) + cNext write ----
    float ex[4][4];
#pragma unroll
    for (int i = 0; i < 4; ++i) {
        float lg[4];
        float m = -1e30f;
#pragma unroll
        for (int c = 0; c < 4; ++c) {
            lg[c] = acc[i][c] / 0.1f;
            m = fmaxf(m, lg[c]);
        }
#pragma unroll
        for (int o = 1; o < 32; o <<= 1) m = fmaxf(m, __shfl_xor(m, o));
        float s = 0.f;
#pragma unroll
        for (int c = 0; c < 4; ++c) {
            ex[i][c] = expf(lg[c] - m);
            s += ex[i][c];
        }
#pragma unroll
        for (int o = 1; o < 32; o <<= 1) s += __shfl_xor(s, o);
        float inv = 1.f / s;
#pragma unroll
        for (int c = 0; c < 4; ++c) ex[i][c] *= inv;
        int p = p0 + mt * 4 + i;
        if (cNext && p < T) {
            *(float4*)&cNext[(size_t)p * HH + nt * 4] =
                make_float4(ex[i][0], ex[i][1], ex[i][2], ex[i][3]);
        }
    }
    // ---- histogram via LDS: stage ex, then 128 column-threads merge root-runs ----
    __syncthreads();  // all As/Bs reads done -> exS may overwrite
#pragma unroll
    for (int i = 0; i < 4; ++i) {
        *(float4*)&exS[mt * 4 + i][nt * 4] =
            make_float4(ex[i][0], ex[i][1], ex[i][2], ex[i][3]);
    }
    __syncthreads();
    if (t < HH) {
        float* fb = feats + it * HH + t;
        float a = 0.f;
        int cur = -1;
        for (int q = 0; q < PTILE; ++q) {
            int r = groots[q];
            if (r < 0) break;
            float v = exS[q][t];
            if (r == cur) {
                a += v;
            } else {
                if (cur >= 0) atomicAdd(&fb[(size_t)cur * NFEAT], a);
                cur = r;
                a = v;
            }
        }
        if (cur >= 0) atomicAdd(&fb[(size_t)cur * NFEAT], a);
    }
}

// ---------------- filter graphs (F=16, M=8): 1024 threads, thread=(node v, chan h) ----------------
__global__ __launch_bounds__(1024) void k_filter(
    const float* __restrict__ P, const float* __restrict__ X,
    const float* __restrict__ E0, const float* __restrict__ R,
    float* __restrict__ filt_feats, float* __restrict__ filt_norm) {
    __shared__ float A_s[64], Am[64], mask_s[8];
    __shared__ float c_s[MM][HH], nb_s[MM][HH];
    __shared__ float fl[NFEAT];
    __shared__ float redm[MM][2], reds[MM][2];
    __shared__ float rr[8];
    int f = blockIdx.x;
    int t = threadIdx.x;
    int v = t >> 7;          // node 0..7
    int h = t & 127;         // channel
    int lane = t & 63;
    int wid = (t >> 6) & 1;  // wave-half within v-group
    if (t < 64) A_s[t] = P[f * 64 + t];
    __syncthreads();
    if (t == 0) {
        float comp[8];
        for (int u = 0; u < 8; ++u) comp[u] = (float)u;
        for (int itr = 0; itr < 8; ++itr) {
            float nm[8];
            for (int u = 0; u < 8; ++u) {
                float mn = 1e9f;
                for (int uu = 0; uu < 8; ++uu)
                    if (A_s[u * 8 + uu] > 0.f) mn = fminf(mn, comp[uu]);
                nm[u] = mn;
            }
            for (int u = 0; u < 8; ++u) comp[u] = fminf(comp[u], nm[u]);
        }
        int counts[8] = {0, 0, 0, 0, 0, 0, 0, 0};
        int ci[8];
        for (int u = 0; u < 8; ++u) {
            ci[u] = (int)comp[u];
            counts[ci[u]]++;
        }
        int best = 0;
        for (int cc = 1; cc < 8; ++cc)
            if (counts[cc] > counts[best]) best = cc;  // first max (ties -> lowest idx)
        for (int u = 0; u < 8; ++u) mask_s[u] = (ci[u] == best) ? 1.f : 0.f;
    }
    __syncthreads();
    if (t < 64) Am[t] = A_s[t] * mask_s[t >> 3] * mask_s[t & 7];
    // c0 = (X @ E0) * mask  (all 8 nodes in parallel)
    {
        float s = 0.f;
        for (int l = 0; l < LL; ++l) s += X[f * MM * LL + v * LL + l] * E0[l * HH + h];
        c_s[v][h] = s * mask_s[v];
    }
    __syncthreads();
    if (v == 0) {
        float s = 0.f;
#pragma unroll
        for (int u = 0; u < 8; ++u) s += c_s[u][h];
        fl[h] = s;
    }
    for (int it = 1; it <= NIT; ++it) {
        // neighbor sum (masked adjacency)
        {
            float s = 0.f;
#pragma unroll
            for (int u = 0; u < 8; ++u) s += Am[v * 8 + u] * c_s[u][h];
            nb_s[v][h] = s;
        }
        __syncthreads();
        // logit for (v,h): own + nbr halves of the signature
        float a0 = 0.f, a1 = 0.f;
        const float* Rp = R + h;
#pragma unroll 4
        for (int k = 0; k < 128; k += 4) {
            float4 cv = *(const float4*)&c_s[v][k];
            float4 nv = *(const float4*)&nb_s[v][k];
            a0 = fmaf(cv.x, Rp[(k + 0) * HH], a0);
            a1 = fmaf(cv.y, Rp[(k + 1) * HH], a1);
            a0 = fmaf(cv.z, Rp[(k + 2) * HH], a0);
            a1 = fmaf(cv.w, Rp[(k + 3) * HH], a1);
            a0 = fmaf(nv.x, Rp[(128 + k + 0) * HH], a0);
            a1 = fmaf(nv.y, Rp[(128 + k + 1) * HH], a1);
            a0 = fmaf(nv.z, Rp[(128 + k + 2) * HH], a0);
            a1 = fmaf(nv.w, Rp[(128 + k + 3) * HH], a1);
        }
        float lg = (a0 + a1) / 0.1f;
        // softmax over h within the v-group (2 waves)
        float m = lg;
        for (int o = 32; o; o >>= 1) m = fmaxf(m, __shfl_xor(m, o));
        if (lane == 0) redm[v][wid] = m;
        __syncthreads();
        m = fmaxf(redm[v][0], redm[v][1]);
        float e = expf(lg - m);
        float ss = e;
        for (int o = 32; o; o >>= 1) ss += __shfl_xor(ss, o);
        if (lane == 0) reds[v][wid] = ss;
        __syncthreads();
        ss = reds[v][0] + reds[v][1];
        float val = (e / ss) * mask_s[v];
        c_s[v][h] = val;  // safe: all logit reads completed before first softmax barrier
        __syncthreads();
        if (v == 0) {
            float s = 0.f;
#pragma unroll
            for (int u = 0; u < 8; ++u) s += c_s[u][h];
            fl[it * HH + h] = s;
        }
        __syncthreads();
    }
    // output + norm: threads 0..511 each own one of the 512 feature slots
    if (t < 512) {
        float val = fl[t];
        filt_feats[f * NFEAT + t] = val;
        float sq = val * val;
        for (int o = 32; o; o >>= 1) sq += __shfl_xor(sq, o);
        if (lane == 0) rr[t >> 6] = sq;
    }
    __syncthreads();
    if (t == 0) {
        float s = 0.f;
#pragma unroll
        for (int u = 0; u < 8; ++u) s += rr[u];
        filt_norm[f] = sqrtf(s);
    }
}

// ---------------- final normalized similarity ----------------
__global__ void k_sim(const float* __restrict__ ego_feats, const float* __restrict__ filt_feats,
                      const float* __restrict__ filt_norm, float* __restrict__ out) {
    __shared__ float red[2];
    int i = blockIdx.x, h = threadIdx.x;
    int lane = h & 63, wid = h >> 6;
    float e0 = ego_feats[i * NFEAT + h];
    float e1 = ego_feats[i * NFEAT + 128 + h];
    float e2 = ego_feats[i * NFEAT + 256 + h];
    float e3 = ego_feats[i * NFEAT + 384 + h];
    float sq = e0 * e0 + e1 * e1 + e2 * e2 + e3 * e3;
    for (int o = 32; o; o >>= 1) sq += __shfl_xor(sq, o);
    if (lane == 0) red[wid] = sq;
    __syncthreads();
    float ng = sqrtf(red[0] + red[1]);
    for (int f = 0; f < FF; ++f) {
        float d = filt_feats[f * NFEAT + h] * e0 + filt_feats[f * NFEAT + 128 + h] * e1 +
                  filt_feats[f * NFEAT + 256 + h] * e2 + filt_feats[f * NFEAT + 384 + h] * e3;
        for (int o = 32; o; o >>= 1) d += __shfl_xor(d, o);
        __syncthreads();
        if (lane == 0) red[wid] = d;
        __syncthreads();
        if (h == 0) out[i * FF + f] = (red[0] + red[1]) / (filt_norm[f] * ng + 1e-12f);
    }
}

extern "C" void kernel_launch(void* const* d_in, const int* in_sizes, int n_in,
                              void* d_out, int out_size, void* d_ws, size_t ws_size,
                              hipStream_t stream) {
    const float* x = (const float*)d_in[0];   // [512,16]
    const int* ei = (const int*)d_in[1];      // [2,2048]
    const float* P = (const float*)d_in[2];   // [16,8,8]
    const float* X = (const float*)d_in[3];   // [16,8,16]
    const float* E0 = (const float*)d_in[4];  // [16,128]
    const float* R = (const float*)d_in[5];   // [256,128]
    float* out = (float*)d_out;               // [512,16]

    char* w = (char*)d_ws;
    auto alloc = [&](size_t bytes) {
        char* p = w;
        w += (bytes + 255) & ~(size_t)255;
        return p;
    };
    unsigned* B0 = (unsigned*)alloc(NN * 16 * 4);
    unsigned* B1 = (unsigned*)alloc(NN * 16 * 4);
    int* cnt = (int*)alloc(NN * 4);
    int* nodeOff = (int*)alloc((NN + 1) * 4);
    int* rootOf = (int*)alloc(TCAP * 4);
    short* nodeIdx = (short*)alloc(TCAP * 2);
    short* list16 = (short*)alloc((size_t)NN * NN * 2);
    short* pos16 = (short*)alloc((size_t)NN * NN * 2);
    int* rowOff = (int*)alloc((size_t)NN * ROSTRIDE * 4);
    short* colIdx = (short*)alloc((size_t)NN * ECAP * 2);
    float* c0_all = (float*)alloc((size_t)NN * HH * 4);
    float* ego_feats = (float*)alloc((size_t)NN * NFEAT * 4);
    float* filt_feats = (float*)alloc((size_t)FF * NFEAT * 4);
    float* filt_norm = (float*)alloc(FF * 4);
    float* cA = (float*)alloc((size_t)TCAP * HH * 4);
    float* cB = (float*)alloc((size_t)TCAP * HH * 4);

    hipMemsetAsync(ego_feats, 0, (size_t)NN * NFEAT * 4, stream);

    k_reach_init<<<64, 128, 0, stream>>>(B0);
    k_copy_u32<<<64, 128, 0, stream>>>(B0, B1, NN * 16);
    k_hop_or<<<512, 128, 0, stream>>>(ei, B0, B1);
    k_copy_u32<<<64, 128, 0, stream>>>(B1, B0, NN * 16);
    k_hop_or<<<512, 128, 0, stream>>>(ei, B1, B0);
    k_compact<<<NN, 64, 0, stream>>>(B0, cnt, list16, pos16);
    k_scan<<<1, NN, 0, stream>>>(cnt, nodeOff);
    k_build_csr<<<NN, 128, 0, stream>>>(ei, cnt, pos16, list16, nodeOff, rowOff, colIdx,
                                        rootOf, nodeIdx);
    k_c0<<<NN, HH, 0, stream>>>(x, E0, c0_all);
    k_feats0<<<NN, HH, 0, stream>>>(cnt, list16, c0_all, ego_feats);

    const int NBLK = (TCAP + PTILE - 1) / PTILE;
    // iter 1: read c0_all via nodeIdx, write cB
    k_projsm<<<NBLK, 256, 0, stream>>>(nodeOff, rootOf, rowOff, colIdx, nodeIdx, c0_all, R, cB,
                                       ego_feats, 1);
    // iter 2: read cB, write cA
    k_projsm<<<NBLK, 256, 0, stream>>>(nodeOff, rootOf, rowOff, colIdx, (const short*)nullptr,
                                       cB, R, cA, ego_feats, 2);
    // iter 3: read cA, histogram only (cNext dead)
    k_projsm<<<NBLK, 256, 0, stream>>>(nodeOff, rootOf, rowOff, colIdx, (const short*)nullptr,
                                       cA, R, (float*)nullptr, ego_feats, 3);

    k_filter<<<FF, 1024, 0, stream>>>(P, X, E0, R, filt_feats, filt_norm);
    k_sim<<<NN, HH, 0, stream>>>(ego_feats, filt_feats, filt_norm, out);
}

// Round 14
// 318.686 us; speedup vs baseline: 1.1939x; 1.1939x over previous
//
#include <hip/hip_runtime.h>
#include <hip/hip_bf16.h>
#include <cstdint>
#include <cstddef>

#define NN 512      // nodes
#define NE 2048     // edges (directed input), symmetrized -> 4096
#define NDIR 4096
#define LL 16       // labels
#define FF 16       // filters
#define MM 8        // filter graph nodes
#define HH 128      // WL hash buckets
#define NIT 3       // WL iterations
#define NFEAT 512   // (NIT+1)*HH
#define TCAP 40960  // max total (root,node) pairs (measured T ~= 35050)
#define ECAP 4096   // per-root internal-edge capacity (hard bound)
#define ROSTRIDE 513
#define PTILE 32    // projsm M-tile
#define SIGW 264    // sig plane row stride in bf16 elems (16B-aligned, stride%32dw==4 -> 2-way frag reads)

using bf16x8 = __attribute__((ext_vector_type(8))) short;
using f32x4 = __attribute__((ext_vector_type(4))) float;
using u16x8 = __attribute__((ext_vector_type(8))) unsigned short;

__device__ __forceinline__ unsigned short f2bf(float x) {
    union { float f; unsigned u; } v; v.f = x;
    unsigned r = v.u + 0x7FFFu + ((v.u >> 16) & 1u);
    return (unsigned short)(r >> 16);
}
__device__ __forceinline__ float bf2f(unsigned short b) {
    union { unsigned u; float f; } v; v.u = ((unsigned)b) << 16; return v.f;
}

// ---------------- reach (2-hop egonet masks) as bitmasks ----------------
__global__ void k_reach_init(unsigned* __restrict__ B) {
    int idx = blockIdx.x * blockDim.x + threadIdx.x;
    if (idx >= NN * 16) return;
    int j = idx >> 4, w = idx & 15;
    B[idx] = (w == (j >> 5)) ? (1u << (j & 31)) : 0u;
}

__global__ void k_copy_u32(const unsigned* __restrict__ s, unsigned* __restrict__ d, int n) {
    int i = blockIdx.x * blockDim.x + threadIdx.x;
    if (i < n) d[i] = s[i];
}

__global__ void k_hop_or(const int* __restrict__ ei, const unsigned* __restrict__ Bold,
                         unsigned* __restrict__ Bnew) {
    int idx = blockIdx.x * blockDim.x + threadIdx.x;
    if (idx >= NDIR * 16) return;
    int e = idx >> 4, w = idx & 15;
    int s = ei[e];
    int d = (e < NE) ? ei[e + NE] : ei[e - NE];
    unsigned v = Bold[s * 16 + w];
    if (v) atomicOr(&Bnew[d * 16 + w], v);
}

// ---------------- per-root compaction (one wave per root, ballot prefix) ----------------
__global__ void k_compact(const unsigned* __restrict__ B, int* __restrict__ cnt,
                          short* __restrict__ list16, short* __restrict__ pos16) {
    int i = blockIdx.x;          // 512 blocks
    int lane = threadIdx.x;      // 64 threads
    int wi = i >> 5;
    unsigned bi = 1u << (i & 31);
    int base = 0;
    for (int j0 = 0; j0 < NN; j0 += 64) {
        int j = j0 + lane;
        bool has = (B[j * 16 + wi] & bi) != 0u;
        unsigned long long mask = __ballot(has);
        int pre = __popcll(mask & ((1ull << lane) - 1ull));
        short pos = -1;
        if (has) {
            pos = (short)(base + pre);
            list16[i * NN + pos] = (short)j;
        }
        pos16[i * NN + j] = pos;
        base += __popcll(mask);
    }
    if (lane == 0) cnt[i] = base;
}

__global__ void k_scan(const int* __restrict__ cnt, int* __restrict__ nodeOff) {
    __shared__ int s[NN];
    int t = threadIdx.x;
    s[t] = cnt[t];
    __syncthreads();
    for (int off = 1; off < NN; off <<= 1) {
        int v = (t >= off) ? s[t - off] : 0;
        __syncthreads();
        s[t] += v;
        __syncthreads();
    }
    nodeOff[t + 1] = s[t];
    if (t == 0) nodeOff[0] = 0;
}

// per-root dst-CSR of internal edges + rootOf/nodeIdx tables
__global__ void k_build_csr(const int* __restrict__ ei, const int* __restrict__ cnt,
                            const short* __restrict__ pos16, const short* __restrict__ list16,
                            const int* __restrict__ nodeOff, int* __restrict__ rowOff,
                            short* __restrict__ colIdx, int* __restrict__ rootOf,
                            short* __restrict__ nodeIdx) {
    __shared__ short pos_s[NN];
    __shared__ int indeg[NN + 1];
    int i = blockIdx.x;
    int t = threadIdx.x;  // 128 threads
    int c = cnt[i];
    int pb = nodeOff[i];
    for (int j = t; j < NN; j += 128) pos_s[j] = pos16[i * NN + j];
    for (int u = t; u <= c; u += 128) indeg[u] = 0;
    for (int u = t; u < c; u += 128) {
        int p = pb + u;
        if (p < TCAP) {
            rootOf[p] = i;
            nodeIdx[p] = list16[i * NN + u];
        }
    }
    __syncthreads();
    for (int e = t; e < NDIR; e += 128) {
        int s = ei[e];
        int d = (e < NE) ? ei[e + NE] : ei[e - NE];
        int sc = pos_s[s], dc = pos_s[d];
        if (sc >= 0 && dc >= 0) atomicAdd(&indeg[dc], 1);
    }
    __syncthreads();
    if (t == 0) {
        int run = 0;
        int* ro = rowOff + i * ROSTRIDE;
        for (int u = 0; u < c; ++u) {
            int v = indeg[u];
            ro[u] = run;
            indeg[u] = run;  // becomes cursor
            run += v;
        }
        ro[c] = run;
    }
    __syncthreads();
    short* col = colIdx + (size_t)i * ECAP;
    for (int e = t; e < NDIR; e += 128) {
        int s = ei[e];
        int d = (e < NE) ? ei[e + NE] : ei[e - NE];
        int sc = pos_s[s], dc = pos_s[d];
        if (sc >= 0 && dc >= 0) {
            int slot = atomicAdd(&indeg[dc], 1);
            col[slot] = (short)sc;
        }
    }
}

// ---------------- initial bucket labels ----------------
__global__ void k_c0(const float* __restrict__ x, const float* __restrict__ E0,
                     float* __restrict__ c0_all) {
    int n = blockIdx.x, h = threadIdx.x;
    float s = 0.f;
    for (int l = 0; l < LL; ++l) s += x[n * LL + l] * E0[l * HH + h];
    c0_all[n * HH + h] = s;
}

// feats slot 0: per-root sum of c0 over egonet (exact: 0/1 values), no atomics
__global__ void k_feats0(const int* __restrict__ cnt, const short* __restrict__ list16,
                         const float* __restrict__ c0_all, float* __restrict__ feats) {
    int i = blockIdx.x, h = threadIdx.x;  // 512 x 128
    int c = cnt[i];
    float s = 0.f;
    for (int u = 0; u < c; ++u) s += c0_all[(size_t)list16[i * NN + u] * HH + h];
    feats[i * NFEAT + h] = s;
}

// ---------------- split R into transposed bf16 hi/lo planes RT[n][k] ----------------
__global__ void k_splitR(const float* __restrict__ R, unsigned short* __restrict__ RTh,
                         unsigned short* __restrict__ RTl) {
    int n = blockIdx.x;    // 128
    int k = threadIdx.x;   // 256
    float x = R[k * HH + n];
    unsigned short h = f2bf(x);
    RTh[n * 256 + k] = h;
    RTl[n * 256 + k] = f2bf(x - bf2f(h));
}

// ---------------- fused WL step: gather + bf16x3 MFMA GEMM + softmax + LDS hist ----
// Prologue: thread (gr=t&31, slice=(t>>5)*16) walks its pair's CSR once; own-c and
// nbr-sum slices split into bf16 hi/lo LDS planes sig[32][256] (c | nbr).
// MFMA: 4 waves x (2 M-tiles x 2 N-tiles) x K=256 in 8 steps x 3 passes
// (HH, HL, LH) of mfma_f32_16x16x32_bf16. A-frags: ds_read_b128 from sig planes
// (lane&15 = row, lane>>4 = k-block). B-frags: global b128 from RT planes (L2-resident).
// Epilogue: D -> exS (union over sigH), row softmax by 8-thread groups, cNext write,
// root-run-merged histogram (128 col-threads).
__global__ __launch_bounds__(256) void k_projsm(
    const int* __restrict__ nodeOff, const int* __restrict__ rootOf,
    const int* __restrict__ rowOff, const short* __restrict__ colIdx,
    const short* __restrict__ nidx, const float* __restrict__ srcC,
    const unsigned short* __restrict__ RTh, const unsigned short* __restrict__ RTl,
    float* __restrict__ cNext, float* __restrict__ feats, int it) {
    __shared__ __align__(16) unsigned short sigH[PTILE][SIGW];  // 16896 B
    __shared__ __align__(16) unsigned short sigL[PTILE][SIGW];  // 16896 B
    __shared__ int groots[PTILE];
    int T = nodeOff[NN];
    if (T > TCAP) T = TCAP;
    int p0 = blockIdx.x * PTILE;
    if (p0 >= T) return;
    int t = threadIdx.x;
    if (t < PTILE) groots[t] = (p0 + t < T) ? rootOf[p0 + t] : -1;
    // ---- prologue: gather + split into bf16 hi/lo planes ----
    {
        int gr = t & 31;
        int gc0 = (t >> 5) * 16;
        float own[16], ga[16];
#pragma unroll
        for (int j = 0; j < 16; ++j) { own[j] = 0.f; ga[j] = 0.f; }
        int p = p0 + gr;
        if (p < T) {
            int i = rootOf[p];
            int pb = nodeOff[i];
            int u = p - pb;
            int srowO = nidx ? (int)nidx[p] : p;
            const float* so = &srcC[(size_t)srowO * HH + gc0];
#pragma unroll
            for (int q4 = 0; q4 < 4; ++q4) {
                float4 v = *(const float4*)&so[q4 * 4];
                own[q4 * 4 + 0] = v.x; own[q4 * 4 + 1] = v.y;
                own[q4 * 4 + 2] = v.z; own[q4 * 4 + 3] = v.w;
            }
            const int* ro = rowOff + i * ROSTRIDE;
            int r0 = ro[u], r1 = ro[u + 1];
            const short* col = colIdx + (size_t)i * ECAP;
            for (int e = r0; e < r1; ++e) {
                int q = pb + col[e];
                int srow = nidx ? (int)nidx[q] : q;
                const float* src = &srcC[(size_t)srow * HH + gc0];
                float4 v0 = *(const float4*)&src[0];
                float4 v1 = *(const float4*)&src[4];
                float4 v2 = *(const float4*)&src[8];
                float4 v3 = *(const float4*)&src[12];
                ga[0] += v0.x;  ga[1] += v0.y;  ga[2] += v0.z;  ga[3] += v0.w;
                ga[4] += v1.x;  ga[5] += v1.y;  ga[6] += v1.z;  ga[7] += v1.w;
                ga[8] += v2.x;  ga[9] += v2.y;  ga[10] += v2.z; ga[11] += v2.w;
                ga[12] += v3.x; ga[13] += v3.y; ga[14] += v3.z; ga[15] += v3.w;
            }
        }
        u16x8 oh[2], ol[2], nh[2], nl[2];
#pragma unroll
        for (int hlf = 0; hlf < 2; ++hlf)
#pragma unroll
            for (int j = 0; j < 8; ++j) {
                float ov = own[hlf * 8 + j], nv = ga[hlf * 8 + j];
                unsigned short ohb = f2bf(ov), nhb = f2bf(nv);
                oh[hlf][j] = ohb; ol[hlf][j] = f2bf(ov - bf2f(ohb));
                nh[hlf][j] = nhb; nl[hlf][j] = f2bf(nv - bf2f(nhb));
            }
#pragma unroll
        for (int hlf = 0; hlf < 2; ++hlf) {
            *(u16x8*)&sigH[gr][gc0 + hlf * 8] = oh[hlf];
            *(u16x8*)&sigL[gr][gc0 + hlf * 8] = ol[hlf];
            *(u16x8*)&sigH[gr][128 + gc0 + hlf * 8] = nh[hlf];
            *(u16x8*)&sigL[gr][128 + gc0 + hlf * 8] = nl[hlf];
        }
    }
    __syncthreads();
    // ---- MFMA: wave w covers cols [32w, 32w+32), both 16-row M-tiles ----
    int w = t >> 6, l = t & 63;
    int lm = l & 15, lk = l >> 4;
    f32x4 acc[2][2];
#pragma unroll
    for (int m = 0; m < 2; ++m)
#pragma unroll
        for (int n = 0; n < 2; ++n)
#pragma unroll
            for (int r = 0; r < 4; ++r) acc[m][n][r] = 0.f;
#pragma unroll
    for (int ks = 0; ks < 8; ++ks) {
        int ko = ks * 32 + lk * 8;
        bf16x8 aH[2], aL[2], bH[2], bL[2];
#pragma unroll
        for (int m = 0; m < 2; ++m) {
            aH[m] = *(const bf16x8*)&sigH[m * 16 + lm][ko];
            aL[m] = *(const bf16x8*)&sigL[m * 16 + lm][ko];
        }
#pragma unroll
        for (int n = 0; n < 2; ++n) {
            size_t cb = (size_t)(w * 32 + n * 16 + lm) * 256 + ko;
            bH[n] = *(const bf16x8*)&RTh[cb];
            bL[n] = *(const bf16x8*)&RTl[cb];
        }
#pragma unroll
        for (int m = 0; m < 2; ++m)
#pragma unroll
            for (int n = 0; n < 2; ++n) {
                acc[m][n] = __builtin_amdgcn_mfma_f32_16x16x32_bf16(aH[m], bH[n], acc[m][n], 0, 0, 0);
                acc[m][n] = __builtin_amdgcn_mfma_f32_16x16x32_bf16(aH[m], bL[n], acc[m][n], 0, 0, 0);
                acc[m][n] = __builtin_amdgcn_mfma_f32_16x16x32_bf16(aL[m], bH[n], acc[m][n], 0, 0, 0);
            }
    }
    // ---- epilogue: stage logits (x10) into exS (union over sigH), softmax, hist ----
    __syncthreads();  // all sigH/sigL reads done
    float (*exS)[132] = (float(*)[132])&sigH[0][0];  // 32*132*4 = 16896 B, exact overlap
#pragma unroll
    for (int m = 0; m < 2; ++m)
#pragma unroll
        for (int n = 0; n < 2; ++n)
#pragma unroll
            for (int r = 0; r < 4; ++r)
                exS[m * 16 + lk * 4 + r][w * 32 + n * 16 + lm] = acc[m][n][r] * 10.0f;
    __syncthreads();
    {
        int rt = t >> 3, cs = (t & 7) * 16;
        float v[16];
#pragma unroll
        for (int q4 = 0; q4 < 4; ++q4) {
            float4 x = *(const float4*)&exS[rt][cs + q4 * 4];
            v[q4 * 4 + 0] = x.x; v[q4 * 4 + 1] = x.y;
            v[q4 * 4 + 2] = x.z; v[q4 * 4 + 3] = x.w;
        }
        float m = v[0];
#pragma unroll
        for (int j = 1; j < 16; ++j) m = fmaxf(m, v[j]);
#pragma unroll
        for (int o = 1; o < 8; o <<= 1) m = fmaxf(m, __shfl_xor(m, o));
        float s = 0.f;
#pragma unroll
        for (int j = 0; j < 16; ++j) { v[j] = expf(v[j] - m); s += v[j]; }
#pragma unroll
        for (int o = 1; o < 8; o <<= 1) s += __shfl_xor(s, o);
        float inv = 1.f / s;
#pragma unroll
        for (int j = 0; j < 16; ++j) v[j] *= inv;
        int p = p0 + rt;
        if (cNext && p < T) {
#pragma unroll
            for (int q4 = 0; q4 < 4; ++q4)
                *(float4*)&cNext[(size_t)p * HH + cs + q4 * 4] =
                    make_float4(v[q4 * 4], v[q4 * 4 + 1], v[q4 * 4 + 2], v[q4 * 4 + 3]);
        }
#pragma unroll
        for (int q4 = 0; q4 < 4; ++q4)
            *(float4*)&exS[rt][cs + q4 * 4] =
                make_float4(v[q4 * 4], v[q4 * 4 + 1], v[q4 * 4 + 2], v[q4 * 4 + 3]);
    }
    __syncthreads();
    if (t < HH) {
        float* fb = feats + it * HH + t;
        float a = 0.f;
        int cur = -1;
        for (int q = 0; q < PTILE; ++q) {
            int r = groots[q];
            if (r < 0) break;
            float v = exS[q][t];
            if (r == cur) {
                a += v;
            } else {
                if (cur >= 0) atomicAdd(&fb[(size_t)cur * NFEAT], a);
                cur = r;
                a = v;
            }
        }
        if (cur >= 0) atomicAdd(&fb[(size_t)cur * NFEAT], a);
    }
}

// ---------------- filter graphs (F=16, M=8): 1024 threads, thread=(node v, chan h) ----------------
__global__ __launch_bounds__(1024) void k_filter(
    const float* __restrict__ P, const float* __restrict__ X,
    const float* __restrict__ E0, const float* __restrict__ R,
    float* __restrict__ filt_feats, float* __restrict__ filt_norm) {
    __shared__ float A_s[64], Am[64], mask_s[8];
    __shared__ float c_s[MM][HH], nb_s[MM][HH];
    __shared__ float fl[NFEAT];
    __shared__ float redm[MM][2], reds[MM][2];
    __shared__ float rr[8];
    int f = blockIdx.x;
    int t = threadIdx.x;
    int v = t >> 7;          // node 0..7
    int h = t & 127;         // channel
    int lane = t & 63;
    int wid = (t >> 6) & 1;  // wave-half within v-group
    if (t < 64) A_s[t] = P[f * 64 + t];
    __syncthreads();
    if (t == 0) {
        float comp[8];
        for (int u = 0; u < 8; ++u) comp[u] = (float)u;
        for (int itr = 0; itr < 8; ++itr) {
            float nm[8];
            for (int u = 0; u < 8; ++u) {
                float mn = 1e9f;
                for (int uu = 0; uu < 8; ++uu)
                    if (A_s[u * 8 + uu] > 0.f) mn = fminf(mn, comp[uu]);
                nm[u] = mn;
            }
            for (int u = 0; u < 8; ++u) comp[u] = fminf(comp[u], nm[u]);
        }
        int counts[8] = {0, 0, 0, 0, 0, 0, 0, 0};
        int ci[8];
        for (int u = 0; u < 8; ++u) {
            ci[u] = (int)comp[u];
            counts[ci[u]]++;
        }
        int best = 0;
        for (int cc = 1; cc < 8; ++cc)
            if (counts[cc] > counts[best]) best = cc;  // first max (ties -> lowest idx)
        for (int u = 0; u < 8; ++u) mask_s[u] = (ci[u] == best) ? 1.f : 0.f;
    }
    __syncthreads();
    if (t < 64) Am[t] = A_s[t] * mask_s[t >> 3] * mask_s[t & 7];
    // c0 = (X @ E0) * mask  (all 8 nodes in parallel)
    {
        float s = 0.f;
        for (int l = 0; l < LL; ++l) s += X[f * MM * LL + v * LL + l] * E0[l * HH + h];
        c_s[v][h] = s * mask_s[v];
    }
    __syncthreads();
    if (v == 0) {
        float s = 0.f;
#pragma unroll
        for (int u = 0; u < 8; ++u) s += c_s[u][h];
        fl[h] = s;
    }
    for (int it = 1; it <= NIT; ++it) {
        // neighbor sum (masked adjacency)
        {
            float s = 0.f;
#pragma unroll
            for (int u = 0; u < 8; ++u) s += Am[v * 8 + u] * c_s[u][h];
            nb_s[v][h] = s;
        }
        __syncthreads();
        // logit for (v,h): own + nbr halves of the signature
        float a0 = 0.f, a1 = 0.f;
        const float* Rp = R + h;
#pragma unroll 4
        for (int k = 0; k < 128; k += 4) {
            float4 cv = *(const float4*)&c_s[v][k];
            float4 nv = *(const float4*)&nb_s[v][k];
            a0 = fmaf(cv.x, Rp[(k + 0) * HH], a0);
            a1 = fmaf(cv.y, Rp[(k + 1) * HH], a1);
            a0 = fmaf(cv.z, Rp[(k + 2) * HH], a0);
            a1 = fmaf(cv.w, Rp[(k + 3) * HH], a1);
            a0 = fmaf(nv.x, Rp[(128 + k + 0) * HH], a0);
            a1 = fmaf(nv.y, Rp[(128 + k + 1) * HH], a1);
            a0 = fmaf(nv.z, Rp[(128 + k + 2) * HH], a0);
            a1 = fmaf(nv.w, Rp[(128 + k + 3) * HH], a1);
        }
        float lg = (a0 + a1) / 0.1f;
        // softmax over h within the v-group (2 waves)
        float m = lg;
        for (int o = 32; o; o >>= 1) m = fmaxf(m, __shfl_xor(m, o));
        if (lane == 0) redm[v][wid] = m;
        __syncthreads();
        m = fmaxf(redm[v][0], redm[v][1]);
        float e = expf(lg - m);
        float ss = e;
        for (int o = 32; o; o >>= 1) ss += __shfl_xor(ss, o);
        if (lane == 0) reds[v][wid] = ss;
        __syncthreads();
        ss = reds[v][0] + reds[v][1];
        float val = (e / ss) * mask_s[v];
        c_s[v][h] = val;  // safe: all logit reads completed before first softmax barrier
        __syncthreads();
        if (v == 0) {
            float s = 0.f;
#pragma unroll
            for (int u = 0; u < 8; ++u) s += c_s[u][h];
            fl[it * HH + h] = s;
        }
        __syncthreads();
    }
    // output + norm: threads 0..511 each own one of the 512 feature slots
    if (t < 512) {
        float val = fl[t];
        filt_feats[f * NFEAT + t] = val;
        float sq = val * val;
        for (int o = 32; o; o >>= 1) sq += __shfl_xor(sq, o);
        if (lane == 0) rr[t >> 6] = sq;
    }
    __syncthreads();
    if (t == 0) {
        float s = 0.f;
#pragma unroll
        for (int u = 0; u < 8; ++u) s += rr[u];
        filt_norm[f] = sqrtf(s);
    }
}

// ---------------- final normalized similarity ----------------
__global__ void k_sim(const float* __restrict__ ego_feats, const float* __restrict__ filt_feats,
                      const float* __restrict__ filt_norm, float* __restrict__ out) {
    __shared__ float red[2];
    int i = blockIdx.x, h = threadIdx.x;
    int lane = h & 63, wid = h >> 6;
    float e0 = ego_feats[i * NFEAT + h];
    float e1 = ego_feats[i * NFEAT + 128 + h];
    float e2 = ego_feats[i * NFEAT + 256 + h];
    float e3 = ego_feats[i * NFEAT + 384 + h];
    float sq = e0 * e0 + e1 * e1 + e2 * e2 + e3 * e3;
    for (int o = 32; o; o >>= 1) sq += __shfl_xor(sq, o);
    if (lane == 0) red[wid] = sq;
    __syncthreads();
    float ng = sqrtf(red[0] + red[1]);
    for (int f = 0; f < FF; ++f) {
        float d = filt_feats[f * NFEAT + h] * e0 + filt_feats[f * NFEAT + 128 + h] * e1 +
                  filt_feats[f * NFEAT + 256 + h] * e2 + filt_feats[f * NFEAT + 384 + h] * e3;
        for (int o = 32; o; o >>= 1) d += __shfl_xor(d, o);
        __syncthreads();
        if (lane == 0) red[wid] = d;
        __syncthreads();
        if (h == 0) out[i * FF + f] = (red[0] + red[1]) / (filt_norm[f] * ng + 1e-12f);
    }
}

extern "C" void kernel_launch(void* const* d_in, const int* in_sizes, int n_in,
                              void* d_out, int out_size, void* d_ws, size_t ws_size,
                              hipStream_t stream) {
    const float* x = (const float*)d_in[0];   // [512,16]
    const int* ei = (const int*)d_in[1];      // [2,2048]
    const float* P = (const float*)d_in[2];   // [16,8,8]
    const float* X = (const float*)d_in[3];   // [16,8,16]
    const float* E0 = (const float*)d_in[4];  // [16,128]
    const float* R = (const float*)d_in[5];   // [256,128]
    float* out = (float*)d_out;               // [512,16]

    char* w = (char*)d_ws;
    auto alloc = [&](size_t bytes) {
        char* p = w;
        w += (bytes + 255) & ~(size_t)255;
        return p;
    };
    unsigned* B0 = (unsigned*)alloc(NN * 16 * 4);
    unsigned* B1 = (unsigned*)alloc(NN * 16 * 4);
    int* cnt = (int*)alloc(NN * 4);
    int* nodeOff = (int*)alloc((NN + 1) * 4);
    int* rootOf = (int*)alloc(TCAP * 4);
    short* nodeIdx = (short*)alloc(TCAP * 2);
    short* list16 = (short*)alloc((size_t)NN * NN * 2);
    short* pos16 = (short*)alloc((size_t)NN * NN * 2);
    int* rowOff = (int*)alloc((size_t)NN * ROSTRIDE * 4);
    short* colIdx = (short*)alloc((size_t)NN * ECAP * 2);
    float* c0_all = (float*)alloc((size_t)NN * HH * 4);
    float* ego_feats = (float*)alloc((size_t)NN * NFEAT * 4);
    float* filt_feats = (float*)alloc((size_t)FF * NFEAT * 4);
    float* filt_norm = (float*)alloc(FF * 4);
    float* cA = (float*)alloc((size_t)TCAP * HH * 4);
    float* cB = (float*)alloc((size_t)TCAP * HH * 4);
    unsigned short* RTh = (unsigned short*)alloc(128 * 256 * 2);
    unsigned short* RTl = (unsigned short*)alloc(128 * 256 * 2);

    hipMemsetAsync(ego_feats, 0, (size_t)NN * NFEAT * 4, stream);

    k_reach_init<<<64, 128, 0, stream>>>(B0);
    k_copy_u32<<<64, 128, 0, stream>>>(B0, B1, NN * 16);
    k_hop_or<<<512, 128, 0, stream>>>(ei, B0, B1);
    k_copy_u32<<<64, 128, 0, stream>>>(B1, B0, NN * 16);
    k_hop_or<<<512, 128, 0, stream>>>(ei, B1, B0);
    k_compact<<<NN, 64, 0, stream>>>(B0, cnt, list16, pos16);
    k_scan<<<1, NN, 0, stream>>>(cnt, nodeOff);
    k_build_csr<<<NN, 128, 0, stream>>>(ei, cnt, pos16, list16, nodeOff, rowOff, colIdx,
                                        rootOf, nodeIdx);
    k_c0<<<NN, HH, 0, stream>>>(x, E0, c0_all);
    k_feats0<<<NN, HH, 0, stream>>>(cnt, list16, c0_all, ego_feats);
    k_splitR<<<128, 256, 0, stream>>>(R, RTh, RTl);

    const int NBLK = (TCAP + PTILE - 1) / PTILE;
    // iter 1: read c0_all via nodeIdx, write cB
    k_projsm<<<NBLK, 256, 0, stream>>>(nodeOff, rootOf, rowOff, colIdx, nodeIdx, c0_all,
                                       RTh, RTl, cB, ego_feats, 1);
    // iter 2: read cB, write cA
    k_projsm<<<NBLK, 256, 0, stream>>>(nodeOff, rootOf, rowOff, colIdx, (const short*)nullptr,
                                       cB, RTh, RTl, cA, ego_feats, 2);
    // iter 3: read cA, histogram only (cNext dead)
    k_projsm<<<NBLK, 256, 0, stream>>>(nodeOff, rootOf, rowOff, colIdx, (const short*)nullptr,
                                       cA, RTh, RTl, (float*)nullptr, ego_feats, 3);

    k_filter<<<FF, 1024, 0, stream>>>(P, X, E0, R, filt_feats, filt_norm);
    k_sim<<<NN, HH, 0, stream>>>(ego_feats, filt_feats, filt_norm, out);
}